// Round 2
// baseline (2133.025 us; speedup 1.0000x reference)
//
#include <hip/hip_runtime.h>
#include <hip/hip_bf16.h>

#define EPS 1e-5f
#define SLOPE 0.01f

typedef short bf16x8 __attribute__((ext_vector_type(8)));  // 8 bf16 in 4 VGPRs
typedef float f32x4  __attribute__((ext_vector_type(4)));

__device__ inline unsigned short f2bf(float f) {
    union { __hip_bfloat16 h; unsigned short u; } cv;
    cv.h = __float2bfloat16(f);
    return cv.u;
}

// ---------------------------------------------------------------------------
// Weight pre-transpose: Wt[k][cout][cin] = bf16(W[k][cin][cout]).
// grid = (Cin/64, K), block = 256.
// ---------------------------------------------------------------------------
__global__ __launch_bounds__(256) void wtrans(
    const float* __restrict__ W, unsigned short* __restrict__ Wt, int Cin)
{
    __shared__ float tl[64][65];
    const int k  = blockIdx.y;
    const int ib = blockIdx.x << 6;
    const int t  = threadIdx.x;
    for (int it = 0; it < 16; ++it) {
        int idx = it * 256 + t, r = idx >> 6, c = idx & 63;
        tl[r][c] = W[(size_t)k * Cin * 64 + (size_t)(ib + r) * 64 + c];
    }
    __syncthreads();
    for (int it = 0; it < 16; ++it) {
        int idx = it * 256 + t, r = idx >> 6, c = idx & 63;  // r=cout, c=cin offset
        Wt[(size_t)k * 64 * Cin + (size_t)r * Cin + ib + c] = f2bf(tl[c][r]);
    }
}

// ---------------------------------------------------------------------------
// CSR build: histogram / scan / fill
// Coarse convs keyed by (dstTile=dst>>6, k); payload = src | dstLocal<<18.
// Up conv keyed by fine row; payload = coarse | k<<16.
// ---------------------------------------------------------------------------
__global__ void hist_coarse(const int* __restrict__ dst, int E, int* __restrict__ cnt) {
    int e = blockIdx.x * 256 + threadIdx.x, k = blockIdx.y;
    if (e < E) atomicAdd(&cnt[(dst[(size_t)k * E + e] >> 6) * 27 + k], 1);
}
__global__ void fill_coarse(const int* __restrict__ src, const int* __restrict__ dst,
                            int E, int* __restrict__ cur, int* __restrict__ elist) {
    int e = blockIdx.x * 256 + threadIdx.x, k = blockIdx.y;
    if (e < E) {
        int d = dst[(size_t)k * E + e];
        int pos = atomicAdd(&cur[(d >> 6) * 27 + k], 1);
        elist[pos] = src[(size_t)k * E + e] | ((d & 63) << 18);
    }
}
__global__ void hist_up(const int* __restrict__ fine, int E, int* __restrict__ cnt) {
    int e = blockIdx.x * 256 + threadIdx.x, k = blockIdx.y;
    if (e < E) atomicAdd(&cnt[fine[(size_t)k * E + e]], 1);
}
__global__ void fill_up(const int* __restrict__ fine, const int* __restrict__ coarse,
                        int E, int* __restrict__ cur, int* __restrict__ elist) {
    int e = blockIdx.x * 256 + threadIdx.x, k = blockIdx.y;
    if (e < E) {
        int f = fine[(size_t)k * E + e];
        int pos = atomicAdd(&cur[f], 1);
        elist[pos] = coarse[(size_t)k * E + e] | (k << 16);
    }
}

// Three independent exclusive scans (one per block), n up to ~26K each.
__global__ __launch_bounds__(256) void scan3(
    int* c0, int* p0, int* u0, int n0,
    int* c1, int* p1, int* u1, int n1,
    int* c2, int* p2, int* u2, int n2)
{
    int *cnt, *ptr, *cur; int n;
    if (blockIdx.x == 0)      { cnt = c0; ptr = p0; cur = u0; n = n0; }
    else if (blockIdx.x == 1) { cnt = c1; ptr = p1; cur = u1; n = n1; }
    else                      { cnt = c2; ptr = p2; cur = u2; n = n2; }
    __shared__ int ls[256];
    __shared__ int base_s;
    const int t = threadIdx.x;
    if (t == 0) base_s = 0;
    __syncthreads();
    for (int chunk = 0; chunk * 1024 < n; ++chunk) {
        int i0 = chunk * 1024 + t * 4;
        int v0 = (i0 + 0 < n) ? cnt[i0 + 0] : 0;
        int v1 = (i0 + 1 < n) ? cnt[i0 + 1] : 0;
        int v2 = (i0 + 2 < n) ? cnt[i0 + 2] : 0;
        int v3 = (i0 + 3 < n) ? cnt[i0 + 3] : 0;
        int tot = v0 + v1 + v2 + v3;
        ls[t] = tot; __syncthreads();
        for (int off = 1; off < 256; off <<= 1) {
            int a = (t >= off) ? ls[t - off] : 0;
            __syncthreads();
            ls[t] += a; __syncthreads();
        }
        int incl = ls[t], bt = ls[255];
        int excl = incl - tot + base_s;
        if (i0 + 0 < n) { ptr[i0 + 0] = excl;               cur[i0 + 0] = excl; }
        if (i0 + 1 < n) { ptr[i0 + 1] = excl + v0;          cur[i0 + 1] = excl + v0; }
        if (i0 + 2 < n) { ptr[i0 + 2] = excl + v0 + v1;     cur[i0 + 2] = excl + v0 + v1; }
        if (i0 + 3 < n) { ptr[i0 + 3] = excl + v0 + v1 + v2; cur[i0 + 3] = excl + v0 + v1 + v2; }
        __syncthreads();
        if (t == 0) base_s += bt;
        __syncthreads();
    }
}

// 3-pass scan for the fine-row CSR (n = Nf = 200000, <=256 chunks of 1024)
__global__ __launch_bounds__(256) void scan_p1(const int* __restrict__ cnt,
                                               int* __restrict__ ptr, int n,
                                               int* __restrict__ tmp) {
    __shared__ int ls[256];
    const int t = threadIdx.x;
    int i0 = blockIdx.x * 1024 + t * 4;
    int v0 = (i0 + 0 < n) ? cnt[i0 + 0] : 0;
    int v1 = (i0 + 1 < n) ? cnt[i0 + 1] : 0;
    int v2 = (i0 + 2 < n) ? cnt[i0 + 2] : 0;
    int v3 = (i0 + 3 < n) ? cnt[i0 + 3] : 0;
    int tot = v0 + v1 + v2 + v3;
    ls[t] = tot; __syncthreads();
    for (int off = 1; off < 256; off <<= 1) {
        int a = (t >= off) ? ls[t - off] : 0;
        __syncthreads();
        ls[t] += a; __syncthreads();
    }
    int excl = ls[t] - tot;
    if (i0 + 0 < n) ptr[i0 + 0] = excl;
    if (i0 + 1 < n) ptr[i0 + 1] = excl + v0;
    if (i0 + 2 < n) ptr[i0 + 2] = excl + v0 + v1;
    if (i0 + 3 < n) ptr[i0 + 3] = excl + v0 + v1 + v2;
    if (t == 255) tmp[blockIdx.x] = ls[255];
}
__global__ __launch_bounds__(256) void scan_p2(int* __restrict__ tmp, int n) {
    __shared__ int ls[256];
    const int t = threadIdx.x;
    int v = (t < n) ? tmp[t] : 0;
    ls[t] = v; __syncthreads();
    for (int off = 1; off < 256; off <<= 1) {
        int a = (t >= off) ? ls[t - off] : 0;
        __syncthreads();
        ls[t] += a; __syncthreads();
    }
    if (t < n) tmp[t] = ls[t] - v;
}
__global__ __launch_bounds__(256) void scan_p3(int* __restrict__ ptr, int* __restrict__ cur,
                                               int n, const int* __restrict__ tmp) {
    int i0 = blockIdx.x * 1024 + threadIdx.x * 4;
    int b = tmp[blockIdx.x];
    #pragma unroll
    for (int j = 0; j < 4; ++j)
        if (i0 + j < n) { int v = ptr[i0 + j] + b; ptr[i0 + j] = v; cur[i0 + j] = v; }
}

// ---------------------------------------------------------------------------
// MFMA gather-GEMM-accumulate conv. Block per 64-row dst tile, 4 waves.
// Each wave owns 16 output channels. Per k: W[k]^T (bf16) in LDS; edges of the
// (tile,k) segment are chunked 16 at a time: gather x rows -> swizzled LDS A
// tile -> mfma_f32_16x16x32_bf16 -> ds_add into LDS row accumulator.
// Output rows written once; per-channel BN stats fused into epilogue.
// LDS 16B-group XOR swizzle by (row&7) keeps both staging and frag reads
// near-conflict-free.
// ---------------------------------------------------------------------------
template<int CIN>
__device__ inline void stage_chunk(const float* __restrict__ x,
                                   const int* __restrict__ elist,
                                   int segB, int len, int ci,
                                   unsigned short* __restrict__ Arow,
                                   int* __restrict__ eL, int t)
{
    const int e = t >> 4;     // edge 0..15
    const int q = t & 15;     // 8B-unit within row (per 64ch half)
    const int j = ci * 16 + e;
    int src = 0;
    bool valid = j < len;
    int ev = 0;
    if (valid) { ev = elist[segB + j]; src = ev & 0x3FFFF; }
    if (q == 0) eL[e] = valid ? (ev >> 18) : 0;
    #pragma unroll
    for (int h = 0; h < CIN / 64; ++h) {
        int u = q + h * 16;                       // 8B unit index (4 bf16)
        ushort4 d = {0, 0, 0, 0};
        if (valid) {
            float4 v = *(const float4*)&x[(size_t)src * CIN + u * 4];
            d.x = f2bf(v.x); d.y = f2bf(v.y); d.z = f2bf(v.z); d.w = f2bf(v.w);
        }
        int g = u >> 1, half = u & 1;
        int pg = (g & ~7) | ((g ^ e) & 7);
        *(ushort4*)&Arow[e * CIN + pg * 8 + half * 4] = d;
    }
}

template<int CIN>
__global__ __launch_bounds__(256) void conv_mfma(
    const float* __restrict__ x, const unsigned short* __restrict__ Wt,
    const int* __restrict__ segPtr, const int* __restrict__ segCnt,
    const int* __restrict__ elist, float* __restrict__ out,
    float* __restrict__ st, int Nc)
{
    constexpr int KSTEPS = CIN / 32;
    __shared__ unsigned short Wl[64 * CIN];
    __shared__ unsigned short At[2][16 * CIN];
    __shared__ int   edL[2][16];
    __shared__ float accs[64 * 64];
    __shared__ float sred[256], qred[256];

    const int t    = threadIdx.x;
    const int tile = blockIdx.x;
    const int tb   = tile << 6;
    const int wv   = t >> 6;
    const int lane = t & 63;
    const int nidx = lane & 15;
    const int quad = lane >> 4;

    for (int i = t; i < 64 * 64; i += 256) accs[i] = 0.f;

    for (int k = 0; k < 27; ++k) {
        __syncthreads();   // protect Wl/At reuse; makes acc init visible at k=0
        // stage W[k]^T (already transposed+bf16 in global) with XOR swizzle
        {
            const unsigned short* Wg = Wt + (size_t)k * 64 * CIN;
            const int c  = t >> 2;
            const int g0 = (t & 3) * (CIN / 32);
            #pragma unroll
            for (int gg = 0; gg < CIN / 32; ++gg) {
                int g = g0 + gg;
                ushort4 lo = *(const ushort4*)&Wg[c * CIN + g * 8];
                ushort4 hi = *(const ushort4*)&Wg[c * CIN + g * 8 + 4];
                int pg = (g & ~7) | ((g ^ c) & 7);
                *(ushort4*)&Wl[c * CIN + pg * 8]     = lo;
                *(ushort4*)&Wl[c * CIN + pg * 8 + 4] = hi;
            }
        }
        const int segB = segPtr[tile * 27 + k];
        const int len  = segCnt[tile * 27 + k];
        const int nch  = (len + 15) >> 4;
        if (nch == 0) continue;
        stage_chunk<CIN>(x, elist, segB, len, 0, At[0], edL[0], t);
        __syncthreads();
        for (int ci = 0; ci < nch; ++ci) {
            const int buf = ci & 1;
            if (ci + 1 < nch)
                stage_chunk<CIN>(x, elist, segB, len, ci + 1, At[buf ^ 1], edL[buf ^ 1], t);
            f32x4 acc = {0.f, 0.f, 0.f, 0.f};
            const int rowb = (wv << 4) + nidx;
            #pragma unroll
            for (int kk = 0; kk < KSTEPS; ++kk) {
                int ga  = kk * 4 + quad;
                int pga = (ga & ~7) | ((ga ^ nidx) & 7);
                int pgb = (ga & ~7) | ((ga ^ rowb) & 7);
                bf16x8 a = *(const bf16x8*)&At[buf][nidx * CIN + pga * 8];
                bf16x8 b = *(const bf16x8*)&Wl[rowb * CIN + pgb * 8];
                acc = __builtin_amdgcn_mfma_f32_16x16x32_bf16(a, b, acc, 0, 0, 0);
            }
            #pragma unroll
            for (int r = 0; r < 4; ++r) {
                int e  = quad * 4 + r;             // C-layout: row = quad*4 + reg
                int dl = edL[buf][e];
                atomicAdd(&accs[dl * 64 + (wv << 4) + nidx], acc[r]);
            }
            if (ci + 1 < nch) __syncthreads();
        }
    }
    __syncthreads();
    // fused per-channel stats (zero rows beyond Nc contribute nothing)
    {
        const int c = t & 63, rg = t >> 6;
        float s = 0.f, qq = 0.f;
        for (int r = rg * 16; r < rg * 16 + 16; ++r) {
            float v = accs[r * 64 + c];
            s += v; qq = fmaf(v, v, qq);
        }
        sred[t] = s; qred[t] = qq;
    }
    __syncthreads();
    if (t < 64) {
        float s  = sred[t] + sred[64 + t] + sred[128 + t] + sred[192 + t];
        float qq = qred[t] + qred[64 + t] + qred[128 + t] + qred[192 + t];
        atomicAdd(&st[t], s);
        atomicAdd(&st[64 + t], qq);
    }
    // write rows once
    {
        const int r = t >> 2, cb = (t & 3) << 4;
        const int row = tb + r;
        if (row < Nc) {
            #pragma unroll
            for (int v = 0; v < 4; ++v)
                *(float4*)&out[(size_t)row * 64 + cb + v * 4] =
                    *(float4*)&accs[r * 64 + cb + v * 4];
        }
    }
}

// ---------------------------------------------------------------------------
// Cout=1 conv over the same (tile,k) segments (reuses csr_g). Wave per edge
// round-robin; shuffle-reduce dot; ds_add into 64-float tile accumulator.
// Fused scalar BN stats.
// ---------------------------------------------------------------------------
__global__ __launch_bounds__(256) void conv_sum_t(
    const float* __restrict__ s, const float* __restrict__ Wsum,
    const int* __restrict__ segPtr, const int* __restrict__ segCnt,
    const int* __restrict__ elist, float* __restrict__ D,
    float* __restrict__ st, int Nc)
{
    __shared__ float acc1[64];
    __shared__ float WsL[64];
    const int t = threadIdx.x, wv = t >> 6, c = t & 63;
    const int tile = blockIdx.x, tb = tile << 6;
    if (t < 64) acc1[t] = 0.f;
    for (int k = 0; k < 27; ++k) {
        __syncthreads();
        if (t < 64) WsL[t] = Wsum[k * 64 + t];
        __syncthreads();
        int segB = segPtr[tile * 27 + k], len = segCnt[tile * 27 + k];
        for (int j = wv; j < len; j += 4) {
            int ev = elist[segB + j];
            int src = ev & 0x3FFFF, dl = ev >> 18;
            float p = s[(size_t)src * 64 + c] * WsL[c];
            for (int off = 32; off; off >>= 1) p += __shfl_down(p, off);
            if (c == 0) atomicAdd(&acc1[dl], p);
        }
    }
    __syncthreads();
    if (t < 64) {
        float v = acc1[t];
        if (tb + t < Nc) D[tb + t] = v;
        float p = v, qq = v * v;
        for (int off = 32; off; off >>= 1) {
            p  += __shfl_down(p, off);
            qq += __shfl_down(qq, off);
        }
        if (t == 0) { atomicAdd(&st[0], p); atomicAdd(&st[1], qq); }
    }
}

// ---------------------------------------------------------------------------
// Cin=1 up-conv, gather form over fine rows (CSR by fine row). All 27x64
// W_up in LDS. Wave per row; fused per-channel stats.
// ---------------------------------------------------------------------------
__global__ __launch_bounds__(256) void conv_up_t(
    const float* __restrict__ s1, const float* __restrict__ Wup,
    const int* __restrict__ rowPtr, const int* __restrict__ rowCnt,
    const int* __restrict__ elist, float* __restrict__ out,
    float* __restrict__ st, int Nf)
{
    __shared__ float WL[27 * 64];
    __shared__ float sred[256], qred[256];
    const int t = threadIdx.x, wv = t >> 6, c = t & 63;
    for (int i = t; i < 27 * 64; i += 256) WL[i] = Wup[i];
    __syncthreads();
    float ssum = 0.f, ssq = 0.f;
    for (int row = blockIdx.x * 4 + wv; row < Nf; row += gridDim.x * 4) {
        int b = rowPtr[row], len = rowCnt[row];
        float acc = 0.f;
        for (int j = 0; j < len; ++j) {
            int ev = elist[b + j];
            float sv = s1[ev & 0xFFFF];
            acc = fmaf(sv, WL[(ev >> 16) * 64 + c], acc);
        }
        out[(size_t)row * 64 + c] = acc;
        ssum += acc; ssq = fmaf(acc, acc, ssq);
    }
    sred[t] = ssum; qred[t] = ssq;
    __syncthreads();
    if (t < 64) {
        float s = sred[t] + sred[64 + t] + sred[128 + t] + sred[192 + t];
        float q = qred[t] + qred[64 + t] + qred[128 + t] + qred[192 + t];
        atomicAdd(&st[t], s);
        atomicAdd(&st[64 + t], q);
    }
}

// ---------------------------------------------------------------------------
// BN apply (64 channels), in-place. ACT 0 = LeakyReLU, 1 = sigmoid.
// Optional += add (after activation), matching s = leaky(bn(C)) + theta.
// ---------------------------------------------------------------------------
template<int ACT>
__global__ __launch_bounds__(256) void bn_f32(
    float* __restrict__ xx, const float* __restrict__ st, int N, float invN,
    const float* __restrict__ gam, const float* __restrict__ bet,
    const float* __restrict__ add)
{
    __shared__ float sc[64], sh[64];
    if (threadIdx.x < 64) {
        int c = threadIdx.x;
        float m = st[c] * invN;
        float v = st[64 + c] * invN - m * m;
        float s = rsqrtf(v + EPS) * gam[c];
        sc[c] = s; sh[c] = bet[c] - m * s;
    }
    __syncthreads();
    size_t n = (size_t)N * 64;
    for (size_t i = (size_t)blockIdx.x * 256 + threadIdx.x; i < n;
         i += (size_t)gridDim.x * 256) {
        int c = (int)(i & 63);
        float y = fmaf(xx[i], sc[c], sh[c]);
        if (ACT == 0) y = (y >= 0.f) ? y : SLOPE * y;
        else          y = 1.f / (1.f + __expf(-y));
        if (add) y += add[i];
        xx[i] = y;
    }
}

__global__ __launch_bounds__(256) void bn1(
    float* __restrict__ x, const float* __restrict__ st, int N, float invN,
    const float* __restrict__ gam, const float* __restrict__ bet)
{
    const float m  = st[0] * invN;
    const float v  = st[1] * invN - m * m;
    const float s  = rsqrtf(v + EPS) * gam[0];
    const float sh = bet[0] - m * s;
    for (int i = blockIdx.x * 256 + threadIdx.x; i < N; i += gridDim.x * 256) {
        float y = fmaf(x[i], s, sh);
        x[i] = (y >= 0.f) ? y : SLOPE * y;
    }
}

// ---------------------------------------------------------------------------
extern "C" void kernel_launch(void* const* d_in, const int* in_sizes, int n_in,
                              void* d_out, int out_size, void* d_ws, size_t ws_size,
                              hipStream_t stream)
{
    const float* gate     = (const float*)d_in[0];
    const float* shortcut = (const float*)d_in[1];
    const int*   src_down = (const int*)d_in[2];
    const int*   dst_down = (const int*)d_in[3];
    const int*   src_g    = (const int*)d_in[4];
    const int*   dst_g    = (const int*)d_in[5];
    const float* W_sc     = (const float*)d_in[6];
    const float* W_g      = (const float*)d_in[8];
    const float* W_gu     = (const float*)d_in[10];
    const float* W_sum    = (const float*)d_in[12];
    const float* W_up     = (const float*)d_in[13];
    const float* gam_sc   = (const float*)d_in[15];
    const float* bet_sc   = (const float*)d_in[16];
    const float* gam_g    = (const float*)d_in[17];
    const float* bet_g    = (const float*)d_in[18];
    const float* gam_gu   = (const float*)d_in[19];
    const float* bet_gu   = (const float*)d_in[20];
    const float* gam_sum  = (const float*)d_in[21];
    const float* bet_sum  = (const float*)d_in[22];
    const float* gam_up   = (const float*)d_in[23];
    const float* bet_up   = (const float*)d_in[24];

    const int K   = 27;
    const int Nc  = in_sizes[0] / 128;   // 60000
    const int Nf  = in_sizes[1] / 64;    // 200000
    const int Ekd = in_sizes[2] / K;     // 40000
    const int Ekg = in_sizes[4] / K;     // 25000
    const int Tc  = (Nc + 63) >> 6;      // coarse tiles
    const int NBc = Tc * 27;             // coarse bins

    // ---- workspace layout (256B-aligned chunks) ----
    char* p = (char*)d_ws;
    auto alloc = [&](size_t bytes) -> void* {
        void* r = (void*)p; p += (bytes + 255) & ~(size_t)255; return r;
    };
    float* ST      = (float*)alloc(640 * 4);            // stats (memset region start)
    int*   cnt_sc  = (int*)alloc((size_t)NBc * 4);
    int*   cnt_g   = (int*)alloc((size_t)NBc * 4);
    int*   cnt_gT  = (int*)alloc((size_t)NBc * 4);
    int*   cnt_up  = (int*)alloc((size_t)Nf * 4);       // memset region end
    size_t zspan   = (size_t)(p - (char*)ST);
    int*   ptr_sc  = (int*)alloc((size_t)NBc * 4);
    int*   cur_sc  = (int*)alloc((size_t)NBc * 4);
    int*   ptr_g   = (int*)alloc((size_t)NBc * 4);
    int*   cur_g   = (int*)alloc((size_t)NBc * 4);
    int*   ptr_gT  = (int*)alloc((size_t)NBc * 4);
    int*   cur_gT  = (int*)alloc((size_t)NBc * 4);
    int*   ptr_up  = (int*)alloc((size_t)Nf * 4);
    int*   cur_up  = (int*)alloc((size_t)Nf * 4);
    int*   stmp    = (int*)alloc(256 * 4);
    int*   el_sc   = (int*)alloc((size_t)K * Ekd * 4);
    int*   el_g    = (int*)alloc((size_t)K * Ekg * 4);
    int*   el_gT   = (int*)alloc((size_t)K * Ekg * 4);
    int*   el_up   = (int*)alloc((size_t)K * Ekd * 4);
    unsigned short* Wt_sc = (unsigned short*)alloc((size_t)K * 64 * 64 * 2);
    unsigned short* Wt_g  = (unsigned short*)alloc((size_t)K * 128 * 64 * 2);
    unsigned short* Wt_gu = (unsigned short*)alloc((size_t)K * 64 * 64 * 2);
    float* A = (float*)alloc((size_t)Nc * 64 * 4);
    float* B = (float*)alloc((size_t)Nc * 64 * 4);
    float* C = (float*)alloc((size_t)Nc * 64 * 4);
    float* D = (float*)alloc((size_t)Nc * 4);
    float* outF = (float*)d_out;

    hipMemsetAsync(ST, 0, zspan, stream);

    const dim3 blk(256);

    // weights -> bf16 transposed
    wtrans<<<dim3(1, K), blk, 0, stream>>>(W_sc, Wt_sc, 64);
    wtrans<<<dim3(2, K), blk, 0, stream>>>(W_g,  Wt_g,  128);
    wtrans<<<dim3(1, K), blk, 0, stream>>>(W_gu, Wt_gu, 64);

    // CSR builds
    const dim3 gEkd((Ekd + 255) / 256, K), gEkg((Ekg + 255) / 256, K);
    hist_coarse<<<gEkd, blk, 0, stream>>>(dst_down, Ekd, cnt_sc);
    hist_coarse<<<gEkg, blk, 0, stream>>>(dst_g,    Ekg, cnt_g);
    hist_coarse<<<gEkg, blk, 0, stream>>>(src_g,    Ekg, cnt_gT);
    hist_up<<<gEkd, blk, 0, stream>>>(src_down, Ekd, cnt_up);
    scan3<<<3, blk, 0, stream>>>(cnt_sc, ptr_sc, cur_sc, NBc,
                                 cnt_g,  ptr_g,  cur_g,  NBc,
                                 cnt_gT, ptr_gT, cur_gT, NBc);
    const int nCh = (Nf + 1023) / 1024;
    scan_p1<<<nCh, blk, 0, stream>>>(cnt_up, ptr_up, Nf, stmp);
    scan_p2<<<1, blk, 0, stream>>>(stmp, nCh);
    scan_p3<<<nCh, blk, 0, stream>>>(ptr_up, cur_up, Nf, stmp);
    fill_coarse<<<gEkd, blk, 0, stream>>>(src_down, dst_down, Ekd, cur_sc, el_sc);
    fill_coarse<<<gEkg, blk, 0, stream>>>(src_g,    dst_g,    Ekg, cur_g,  el_g);
    fill_coarse<<<gEkg, blk, 0, stream>>>(dst_g,    src_g,    Ekg, cur_gT, el_gT);
    fill_up<<<gEkd, blk, 0, stream>>>(src_down, dst_down, Ekd, cur_up, el_up);

    // theta = leaky(bn(sconv(shortcut, W_sc)))
    conv_mfma<64><<<Tc, blk, 0, stream>>>(shortcut, Wt_sc, ptr_sc, cnt_sc, el_sc,
                                          A, ST + 0, Nc);
    // phi_raw = sconv(gate, W_g)
    conv_mfma<128><<<Tc, blk, 0, stream>>>(gate, Wt_g, ptr_g, cnt_g, el_g,
                                           B, ST + 128, Nc);
    bn_f32<0><<<1024, blk, 0, stream>>>(A, ST + 0,   Nc, 1.f / Nc, gam_sc, bet_sc, nullptr);
    bn_f32<0><<<1024, blk, 0, stream>>>(B, ST + 128, Nc, 1.f / Nc, gam_g,  bet_g,  nullptr);
    // phi = leaky(bn(sconv(phi, W_gu, transposed pairs)))
    conv_mfma<64><<<Tc, blk, 0, stream>>>(B, Wt_gu, ptr_gT, cnt_gT, el_gT,
                                          C, ST + 256, Nc);
    // s = leaky(bn(C)) + theta
    bn_f32<0><<<1024, blk, 0, stream>>>(C, ST + 256, Nc, 1.f / Nc, gam_gu, bet_gu, A);
    // s1 = leaky(bn(sconv(s, W_sum)))
    conv_sum_t<<<Tc, blk, 0, stream>>>(C, W_sum, ptr_g, cnt_g, el_g, D, ST + 384, Nc);
    bn1<<<256, blk, 0, stream>>>(D, ST + 384, Nc, 1.f / Nc, gam_sum, bet_sum);
    // out = sigmoid(bn(sconv(s1, W_up, inverse pairs)))
    conv_up_t<<<2048, blk, 0, stream>>>(D, W_up, ptr_up, cnt_up, el_up,
                                        outF, ST + 448, Nf);
    bn_f32<1><<<2048, blk, 0, stream>>>(outF, ST + 448, Nf, 1.f / Nf, gam_up, bet_up, nullptr);
}

// Round 4
// 1978.213 us; speedup vs baseline: 1.0783x; 1.0783x over previous
//
#include <hip/hip_runtime.h>
#include <hip/hip_bf16.h>

#define EPS 1e-5f
#define SLOPE 0.01f

typedef short bf16x8 __attribute__((ext_vector_type(8)));  // 8 bf16 in 4 VGPRs
typedef float f32x4  __attribute__((ext_vector_type(4)));

__device__ inline unsigned short f2bf(float f) {
    union { __hip_bfloat16 h; unsigned short u; } cv;
    cv.h = __float2bfloat16(f);
    return cv.u;
}

// ---------------------------------------------------------------------------
// Weight pre-transpose: Wt[k][cout][cin] = bf16(W[k][cin][cout]).
// grid = (Cin/64, K), block = 256.
// ---------------------------------------------------------------------------
__global__ __launch_bounds__(256) void wtrans(
    const float* __restrict__ W, unsigned short* __restrict__ Wt, int Cin)
{
    __shared__ float tl[64][65];
    const int k  = blockIdx.y;
    const int ib = blockIdx.x << 6;
    const int t  = threadIdx.x;
    for (int it = 0; it < 16; ++it) {
        int idx = it * 256 + t, r = idx >> 6, c = idx & 63;
        tl[r][c] = W[(size_t)k * Cin * 64 + (size_t)(ib + r) * 64 + c];
    }
    __syncthreads();
    for (int it = 0; it < 16; ++it) {
        int idx = it * 256 + t, r = idx >> 6, c = idx & 63;  // r=cout, c=cin offset
        Wt[(size_t)k * 64 * Cin + (size_t)r * Cin + ib + c] = f2bf(tl[c][r]);
    }
}

// ---------------------------------------------------------------------------
// CSR build: histogram / scan / fill
// Coarse convs keyed by (dstTile=dst>>6, k); payload = src | dstLocal<<18.
// Up conv keyed by fine row; payload = coarse | k<<16.
// ---------------------------------------------------------------------------
__global__ void hist_coarse(const int* __restrict__ dst, int E, int* __restrict__ cnt) {
    int e = blockIdx.x * 256 + threadIdx.x, k = blockIdx.y;
    if (e < E) atomicAdd(&cnt[(dst[(size_t)k * E + e] >> 6) * 27 + k], 1);
}
__global__ void fill_coarse(const int* __restrict__ src, const int* __restrict__ dst,
                            int E, int* __restrict__ cur, int* __restrict__ elist) {
    int e = blockIdx.x * 256 + threadIdx.x, k = blockIdx.y;
    if (e < E) {
        int d = dst[(size_t)k * E + e];
        int pos = atomicAdd(&cur[(d >> 6) * 27 + k], 1);
        elist[pos] = src[(size_t)k * E + e] | ((d & 63) << 18);
    }
}
__global__ void hist_up(const int* __restrict__ fine, int E, int* __restrict__ cnt) {
    int e = blockIdx.x * 256 + threadIdx.x, k = blockIdx.y;
    if (e < E) atomicAdd(&cnt[fine[(size_t)k * E + e]], 1);
}
__global__ void fill_up(const int* __restrict__ fine, const int* __restrict__ coarse,
                        int E, int* __restrict__ cur, int* __restrict__ elist) {
    int e = blockIdx.x * 256 + threadIdx.x, k = blockIdx.y;
    if (e < E) {
        int f = fine[(size_t)k * E + e];
        int pos = atomicAdd(&cur[f], 1);
        elist[pos] = coarse[(size_t)k * E + e] | (k << 16);
    }
}

// Three independent exclusive scans (one per block), n up to ~26K each.
__global__ __launch_bounds__(256) void scan3(
    int* c0, int* p0, int* u0, int n0,
    int* c1, int* p1, int* u1, int n1,
    int* c2, int* p2, int* u2, int n2)
{
    int *cnt, *ptr, *cur; int n;
    if (blockIdx.x == 0)      { cnt = c0; ptr = p0; cur = u0; n = n0; }
    else if (blockIdx.x == 1) { cnt = c1; ptr = p1; cur = u1; n = n1; }
    else                      { cnt = c2; ptr = p2; cur = u2; n = n2; }
    __shared__ int ls[256];
    __shared__ int base_s;
    const int t = threadIdx.x;
    if (t == 0) base_s = 0;
    __syncthreads();
    for (int chunk = 0; chunk * 1024 < n; ++chunk) {
        int i0 = chunk * 1024 + t * 4;
        int v0 = (i0 + 0 < n) ? cnt[i0 + 0] : 0;
        int v1 = (i0 + 1 < n) ? cnt[i0 + 1] : 0;
        int v2 = (i0 + 2 < n) ? cnt[i0 + 2] : 0;
        int v3 = (i0 + 3 < n) ? cnt[i0 + 3] : 0;
        int tot = v0 + v1 + v2 + v3;
        ls[t] = tot; __syncthreads();
        for (int off = 1; off < 256; off <<= 1) {
            int a = (t >= off) ? ls[t - off] : 0;
            __syncthreads();
            ls[t] += a; __syncthreads();
        }
        int incl = ls[t], bt = ls[255];
        int excl = incl - tot + base_s;
        if (i0 + 0 < n) { ptr[i0 + 0] = excl;               cur[i0 + 0] = excl; }
        if (i0 + 1 < n) { ptr[i0 + 1] = excl + v0;          cur[i0 + 1] = excl + v0; }
        if (i0 + 2 < n) { ptr[i0 + 2] = excl + v0 + v1;     cur[i0 + 2] = excl + v0 + v1; }
        if (i0 + 3 < n) { ptr[i0 + 3] = excl + v0 + v1 + v2; cur[i0 + 3] = excl + v0 + v1 + v2; }
        __syncthreads();
        if (t == 0) base_s += bt;
        __syncthreads();
    }
}

// 3-pass scan for the fine-row CSR (n = Nf = 200000, <=256 chunks of 1024)
__global__ __launch_bounds__(256) void scan_p1(const int* __restrict__ cnt,
                                               int* __restrict__ ptr, int n,
                                               int* __restrict__ tmp) {
    __shared__ int ls[256];
    const int t = threadIdx.x;
    int i0 = blockIdx.x * 1024 + t * 4;
    int v0 = (i0 + 0 < n) ? cnt[i0 + 0] : 0;
    int v1 = (i0 + 1 < n) ? cnt[i0 + 1] : 0;
    int v2 = (i0 + 2 < n) ? cnt[i0 + 2] : 0;
    int v3 = (i0 + 3 < n) ? cnt[i0 + 3] : 0;
    int tot = v0 + v1 + v2 + v3;
    ls[t] = tot; __syncthreads();
    for (int off = 1; off < 256; off <<= 1) {
        int a = (t >= off) ? ls[t - off] : 0;
        __syncthreads();
        ls[t] += a; __syncthreads();
    }
    int excl = ls[t] - tot;
    if (i0 + 0 < n) ptr[i0 + 0] = excl;
    if (i0 + 1 < n) ptr[i0 + 1] = excl + v0;
    if (i0 + 2 < n) ptr[i0 + 2] = excl + v0 + v1;
    if (i0 + 3 < n) ptr[i0 + 3] = excl + v0 + v1 + v2;
    if (t == 255) tmp[blockIdx.x] = ls[255];
}
__global__ __launch_bounds__(256) void scan_p2(int* __restrict__ tmp, int n) {
    __shared__ int ls[256];
    const int t = threadIdx.x;
    int v = (t < n) ? tmp[t] : 0;
    ls[t] = v; __syncthreads();
    for (int off = 1; off < 256; off <<= 1) {
        int a = (t >= off) ? ls[t - off] : 0;
        __syncthreads();
        ls[t] += a; __syncthreads();
    }
    if (t < n) tmp[t] = ls[t] - v;
}
__global__ __launch_bounds__(256) void scan_p3(int* __restrict__ ptr, int* __restrict__ cur,
                                               int n, const int* __restrict__ tmp) {
    int i0 = blockIdx.x * 1024 + threadIdx.x * 4;
    int b = tmp[blockIdx.x];
    #pragma unroll
    for (int j = 0; j < 4; ++j)
        if (i0 + j < n) { int v = ptr[i0 + j] + b; ptr[i0 + j] = v; cur[i0 + j] = v; }
}

// ---------------------------------------------------------------------------
// MFMA gather-GEMM conv, barrier-free main loop.
// Block per 64-row dst tile, 8 waves (512 thr). Chunks (16 edges) are
// distributed round-robin across waves (cid%8==wv); EACH WAVE COMPUTES ALL
// 64 OUTPUT CHANNELS for its chunks (B-fragments for all 4 cout groups held
// in registers, hoisted per k) -- this fixes round 3's dropped-cout bug.
// A-fragments gathered directly global->regs (lane nidx = edge, quad = k
// block of 8 contiguous channels). Accumulate into shared 64x64 LDS tile via
// atomicAdd. Only 2 block barriers. BN stats fused; rows written once.
// ---------------------------------------------------------------------------
template<int CIN>
__global__ __launch_bounds__(512) void conv_mfma(
    const float* __restrict__ x, const unsigned short* __restrict__ Wt,
    const int* __restrict__ segPtr, const int* __restrict__ segCnt,
    const int* __restrict__ elist, float* __restrict__ out,
    float* __restrict__ st, int Nc)
{
    constexpr int KS = CIN / 32;
    __shared__ float accs[64 * 64];
    __shared__ float sred[512], qred[512];

    const int t    = threadIdx.x;
    const int tile = blockIdx.x;
    const int tb   = tile << 6;
    const int wv   = t >> 6;            // 0..7
    const int lane = t & 63;
    const int nidx = lane & 15;         // edge-in-chunk / n index
    const int quad = lane >> 4;

    for (int i = t; i < 64 * 64; i += 512) accs[i] = 0.f;
    __syncthreads();

    int cid = 0;   // global chunk counter across k (uniform in block)
    for (int k = 0; k < 27; ++k) {
        const int segB = segPtr[tile * 27 + k];
        const int len  = segCnt[tile * 27 + k];
        const int nch  = (len + 15) >> 4;
        if (nch == 0) continue;
        const int first = (wv - cid) & 7;         // my first chunk offset in this k
        if (first < nch) {
            // B fragments for ALL 4 cout groups (per-k constant, L1-resident)
            bf16x8 bf[4][KS];
            const unsigned short* WgB = Wt + (size_t)k * 64 * CIN;
            #pragma unroll
            for (int g = 0; g < 4; ++g) {
                const unsigned short* Wg = WgB + (size_t)(g * 16 + nidx) * CIN;
                #pragma unroll
                for (int kk = 0; kk < KS; ++kk)
                    bf[g][kk] = *(const bf16x8*)&Wg[kk * 32 + quad * 8];
            }
            for (int ic = first; ic < nch; ic += 8) {
                const int jn  = ic * 16 + nidx;    // my edge index in segment
                const bool val = jn < len;
                int ev = 0;
                if (val) ev = elist[segB + jn];
                const int src = ev & 0x3FFFF;

                bf16x8 af[KS];
                #pragma unroll
                for (int kk = 0; kk < KS; ++kk)
                    #pragma unroll
                    for (int j = 0; j < 8; ++j) af[kk][j] = 0;
                if (val) {
                    const float* xr = x + (size_t)src * CIN + quad * 8;
                    #pragma unroll
                    for (int kk = 0; kk < KS; ++kk) {
                        const float4 lo = *(const float4*)(xr + kk * 32);
                        const float4 hi = *(const float4*)(xr + kk * 32 + 4);
                        af[kk][0] = f2bf(lo.x); af[kk][1] = f2bf(lo.y);
                        af[kk][2] = f2bf(lo.z); af[kk][3] = f2bf(lo.w);
                        af[kk][4] = f2bf(hi.x); af[kk][5] = f2bf(hi.y);
                        af[kk][6] = f2bf(hi.z); af[kk][7] = f2bf(hi.w);
                    }
                }
                f32x4 acc[4];
                #pragma unroll
                for (int g = 0; g < 4; ++g) acc[g] = (f32x4){0.f, 0.f, 0.f, 0.f};
                #pragma unroll
                for (int kk = 0; kk < KS; ++kk)
                    #pragma unroll
                    for (int g = 0; g < 4; ++g)
                        acc[g] = __builtin_amdgcn_mfma_f32_16x16x32_bf16(
                            af[kk], bf[g][kk], acc[g], 0, 0, 0);
                // D layout: row(edge) = quad*4+r, col = nidx (cout g*16+nidx).
                // Edge e's ev lives in lane e (quad 0, nidx=e) -> shfl.
                #pragma unroll
                for (int r = 0; r < 4; ++r) {
                    const int e   = quad * 4 + r;
                    const int evE = __shfl(ev, e);
                    const int dl  = (evE >> 18) & 63;   // padded edges add 0.0
                    #pragma unroll
                    for (int g = 0; g < 4; ++g)
                        atomicAdd(&accs[dl * 64 + g * 16 + nidx], acc[g][r]);
                }
            }
        }
        cid += nch;
    }
    __syncthreads();
    // fused per-channel BN stats (rows beyond Nc are zero -> no contribution)
    {
        const int c = t & 63, rg = t >> 6;   // 8 row-groups of 8
        float s = 0.f, qq = 0.f;
        for (int r = rg * 8; r < rg * 8 + 8; ++r) {
            const float v = accs[r * 64 + c];
            s += v; qq = fmaf(v, v, qq);
        }
        sred[t] = s; qred[t] = qq;
    }
    __syncthreads();
    if (t < 64) {
        float s = 0.f, qq = 0.f;
        #pragma unroll
        for (int g = 0; g < 8; ++g) { s += sred[g * 64 + t]; qq += qred[g * 64 + t]; }
        atomicAdd(&st[t], s);
        atomicAdd(&st[64 + t], qq);
    }
    // write rows once (coalesced float4)
    {
        const int r = t >> 3, cb = (t & 7) << 3;
        const int row = tb + r;
        if (row < Nc) {
            *(float4*)&out[(size_t)row * 64 + cb]     = *(float4*)&accs[r * 64 + cb];
            *(float4*)&out[(size_t)row * 64 + cb + 4] = *(float4*)&accs[r * 64 + cb + 4];
        }
    }
}

// ---------------------------------------------------------------------------
// Cout=1 conv over the same (tile,k) segments (reuses csr_g). Wave per edge
// round-robin; shuffle-reduce dot; LDS-atomic into 64-float tile accumulator.
// Fused scalar BN stats.
// ---------------------------------------------------------------------------
__global__ __launch_bounds__(256) void conv_sum_t(
    const float* __restrict__ s, const float* __restrict__ Wsum,
    const int* __restrict__ segPtr, const int* __restrict__ segCnt,
    const int* __restrict__ elist, float* __restrict__ D,
    float* __restrict__ st, int Nc)
{
    __shared__ float acc1[64];
    __shared__ float WsL[64];
    const int t = threadIdx.x, wv = t >> 6, c = t & 63;
    const int tile = blockIdx.x, tb = tile << 6;
    if (t < 64) acc1[t] = 0.f;
    for (int k = 0; k < 27; ++k) {
        __syncthreads();
        if (t < 64) WsL[t] = Wsum[k * 64 + t];
        __syncthreads();
        int segB = segPtr[tile * 27 + k], len = segCnt[tile * 27 + k];
        for (int j = wv; j < len; j += 4) {
            int ev = elist[segB + j];
            int src = ev & 0x3FFFF, dl = ev >> 18;
            float p = s[(size_t)src * 64 + c] * WsL[c];
            for (int off = 32; off; off >>= 1) p += __shfl_down(p, off);
            if (c == 0) atomicAdd(&acc1[dl], p);
        }
    }
    __syncthreads();
    if (t < 64) {
        float v = acc1[t];
        if (tb + t < Nc) D[tb + t] = v;
        float p = v, qq = v * v;
        for (int off = 32; off; off >>= 1) {
            p  += __shfl_down(p, off);
            qq += __shfl_down(qq, off);
        }
        if (t == 0) { atomicAdd(&st[0], p); atomicAdd(&st[1], qq); }
    }
}

// ---------------------------------------------------------------------------
// Cin=1 up-conv, gather form over fine rows (CSR by fine row). All 27x64
// W_up in LDS. Wave per row; fused per-channel stats.
// ---------------------------------------------------------------------------
__global__ __launch_bounds__(256) void conv_up_t(
    const float* __restrict__ s1, const float* __restrict__ Wup,
    const int* __restrict__ rowPtr, const int* __restrict__ rowCnt,
    const int* __restrict__ elist, float* __restrict__ out,
    float* __restrict__ st, int Nf)
{
    __shared__ float WL[27 * 64];
    __shared__ float sred[256], qred[256];
    const int t = threadIdx.x, wv = t >> 6, c = t & 63;
    for (int i = t; i < 27 * 64; i += 256) WL[i] = Wup[i];
    __syncthreads();
    float ssum = 0.f, ssq = 0.f;
    for (int row = blockIdx.x * 4 + wv; row < Nf; row += gridDim.x * 4) {
        int b = rowPtr[row], len = rowCnt[row];
        float acc = 0.f;
        for (int j = 0; j < len; ++j) {
            int ev = elist[b + j];
            float sv = s1[ev & 0xFFFF];
            acc = fmaf(sv, WL[(ev >> 16) * 64 + c], acc);
        }
        out[(size_t)row * 64 + c] = acc;
        ssum += acc; ssq = fmaf(acc, acc, ssq);
    }
    sred[t] = ssum; qred[t] = ssq;
    __syncthreads();
    if (t < 64) {
        float s = sred[t] + sred[64 + t] + sred[128 + t] + sred[192 + t];
        float q = qred[t] + qred[64 + t] + qred[128 + t] + qred[192 + t];
        atomicAdd(&st[t], s);
        atomicAdd(&st[64 + t], q);
    }
}

// ---------------------------------------------------------------------------
// BN apply (64 channels), in-place. ACT 0 = LeakyReLU, 1 = sigmoid.
// Optional += add (after activation), matching s = leaky(bn(C)) + theta.
// ---------------------------------------------------------------------------
template<int ACT>
__global__ __launch_bounds__(256) void bn_f32(
    float* __restrict__ xx, const float* __restrict__ st, int N, float invN,
    const float* __restrict__ gam, const float* __restrict__ bet,
    const float* __restrict__ add)
{
    __shared__ float sc[64], sh[64];
    if (threadIdx.x < 64) {
        int c = threadIdx.x;
        float m = st[c] * invN;
        float v = st[64 + c] * invN - m * m;
        float s = rsqrtf(v + EPS) * gam[c];
        sc[c] = s; sh[c] = bet[c] - m * s;
    }
    __syncthreads();
    size_t n = (size_t)N * 64;
    for (size_t i = (size_t)blockIdx.x * 256 + threadIdx.x; i < n;
         i += (size_t)gridDim.x * 256) {
        int c = (int)(i & 63);
        float y = fmaf(xx[i], sc[c], sh[c]);
        if (ACT == 0) y = (y >= 0.f) ? y : SLOPE * y;
        else          y = 1.f / (1.f + __expf(-y));
        if (add) y += add[i];
        xx[i] = y;
    }
}

__global__ __launch_bounds__(256) void bn1(
    float* __restrict__ x, const float* __restrict__ st, int N, float invN,
    const float* __restrict__ gam, const float* __restrict__ bet)
{
    const float m  = st[0] * invN;
    const float v  = st[1] * invN - m * m;
    const float s  = rsqrtf(v + EPS) * gam[0];
    const float sh = bet[0] - m * s;
    for (int i = blockIdx.x * 256 + threadIdx.x; i < N; i += gridDim.x * 256) {
        float y = fmaf(x[i], s, sh);
        x[i] = (y >= 0.f) ? y : SLOPE * y;
    }
}

// ---------------------------------------------------------------------------
extern "C" void kernel_launch(void* const* d_in, const int* in_sizes, int n_in,
                              void* d_out, int out_size, void* d_ws, size_t ws_size,
                              hipStream_t stream)
{
    const float* gate     = (const float*)d_in[0];
    const float* shortcut = (const float*)d_in[1];
    const int*   src_down = (const int*)d_in[2];
    const int*   dst_down = (const int*)d_in[3];
    const int*   src_g    = (const int*)d_in[4];
    const int*   dst_g    = (const int*)d_in[5];
    const float* W_sc     = (const float*)d_in[6];
    const float* W_g      = (const float*)d_in[8];
    const float* W_gu     = (const float*)d_in[10];
    const float* W_sum    = (const float*)d_in[12];
    const float* W_up     = (const float*)d_in[13];
    const float* gam_sc   = (const float*)d_in[15];
    const float* bet_sc   = (const float*)d_in[16];
    const float* gam_g    = (const float*)d_in[17];
    const float* bet_g    = (const float*)d_in[18];
    const float* gam_gu   = (const float*)d_in[19];
    const float* bet_gu   = (const float*)d_in[20];
    const float* gam_sum  = (const float*)d_in[21];
    const float* bet_sum  = (const float*)d_in[22];
    const float* gam_up   = (const float*)d_in[23];
    const float* bet_up   = (const float*)d_in[24];

    const int K   = 27;
    const int Nc  = in_sizes[0] / 128;   // 60000
    const int Nf  = in_sizes[1] / 64;    // 200000
    const int Ekd = in_sizes[2] / K;     // 40000
    const int Ekg = in_sizes[4] / K;     // 25000
    const int Tc  = (Nc + 63) >> 6;      // coarse tiles
    const int NBc = Tc * 27;             // coarse bins

    // ---- workspace layout (256B-aligned chunks) ----
    char* p = (char*)d_ws;
    auto alloc = [&](size_t bytes) -> void* {
        void* r = (void*)p; p += (bytes + 255) & ~(size_t)255; return r;
    };
    float* ST      = (float*)alloc(640 * 4);            // stats (memset region start)
    int*   cnt_sc  = (int*)alloc((size_t)NBc * 4);
    int*   cnt_g   = (int*)alloc((size_t)NBc * 4);
    int*   cnt_gT  = (int*)alloc((size_t)NBc * 4);
    int*   cnt_up  = (int*)alloc((size_t)Nf * 4);       // memset region end
    size_t zspan   = (size_t)(p - (char*)ST);
    int*   ptr_sc  = (int*)alloc((size_t)NBc * 4);
    int*   cur_sc  = (int*)alloc((size_t)NBc * 4);
    int*   ptr_g   = (int*)alloc((size_t)NBc * 4);
    int*   cur_g   = (int*)alloc((size_t)NBc * 4);
    int*   ptr_gT  = (int*)alloc((size_t)NBc * 4);
    int*   cur_gT  = (int*)alloc((size_t)NBc * 4);
    int*   ptr_up  = (int*)alloc((size_t)Nf * 4);
    int*   cur_up  = (int*)alloc((size_t)Nf * 4);
    int*   stmp    = (int*)alloc(256 * 4);
    int*   el_sc   = (int*)alloc((size_t)K * Ekd * 4);
    int*   el_g    = (int*)alloc((size_t)K * Ekg * 4);
    int*   el_gT   = (int*)alloc((size_t)K * Ekg * 4);
    int*   el_up   = (int*)alloc((size_t)K * Ekd * 4);
    unsigned short* Wt_sc = (unsigned short*)alloc((size_t)K * 64 * 64 * 2);
    unsigned short* Wt_g  = (unsigned short*)alloc((size_t)K * 128 * 64 * 2);
    unsigned short* Wt_gu = (unsigned short*)alloc((size_t)K * 64 * 64 * 2);
    float* A = (float*)alloc((size_t)Nc * 64 * 4);
    float* B = (float*)alloc((size_t)Nc * 64 * 4);
    float* C = (float*)alloc((size_t)Nc * 64 * 4);
    float* D = (float*)alloc((size_t)Nc * 4);
    float* outF = (float*)d_out;

    hipMemsetAsync(ST, 0, zspan, stream);

    const dim3 blk(256);

    // weights -> bf16 transposed
    wtrans<<<dim3(1, K), blk, 0, stream>>>(W_sc, Wt_sc, 64);
    wtrans<<<dim3(2, K), blk, 0, stream>>>(W_g,  Wt_g,  128);
    wtrans<<<dim3(1, K), blk, 0, stream>>>(W_gu, Wt_gu, 64);

    // CSR builds
    const dim3 gEkd((Ekd + 255) / 256, K), gEkg((Ekg + 255) / 256, K);
    hist_coarse<<<gEkd, blk, 0, stream>>>(dst_down, Ekd, cnt_sc);
    hist_coarse<<<gEkg, blk, 0, stream>>>(dst_g,    Ekg, cnt_g);
    hist_coarse<<<gEkg, blk, 0, stream>>>(src_g,    Ekg, cnt_gT);
    hist_up<<<gEkd, blk, 0, stream>>>(src_down, Ekd, cnt_up);
    scan3<<<3, blk, 0, stream>>>(cnt_sc, ptr_sc, cur_sc, NBc,
                                 cnt_g,  ptr_g,  cur_g,  NBc,
                                 cnt_gT, ptr_gT, cur_gT, NBc);
    const int nCh = (Nf + 1023) / 1024;
    scan_p1<<<nCh, blk, 0, stream>>>(cnt_up, ptr_up, Nf, stmp);
    scan_p2<<<1, blk, 0, stream>>>(stmp, nCh);
    scan_p3<<<nCh, blk, 0, stream>>>(ptr_up, cur_up, Nf, stmp);
    fill_coarse<<<gEkd, blk, 0, stream>>>(src_down, dst_down, Ekd, cur_sc, el_sc);
    fill_coarse<<<gEkg, blk, 0, stream>>>(src_g,    dst_g,    Ekg, cur_g,  el_g);
    fill_coarse<<<gEkg, blk, 0, stream>>>(dst_g,    src_g,    Ekg, cur_gT, el_gT);
    fill_up<<<gEkd, blk, 0, stream>>>(src_down, dst_down, Ekd, cur_up, el_up);

    // theta = leaky(bn(sconv(shortcut, W_sc)))
    conv_mfma<64><<<Tc, dim3(512), 0, stream>>>(shortcut, Wt_sc, ptr_sc, cnt_sc, el_sc,
                                                A, ST + 0, Nc);
    // phi_raw = sconv(gate, W_g)
    conv_mfma<128><<<Tc, dim3(512), 0, stream>>>(gate, Wt_g, ptr_g, cnt_g, el_g,
                                                 B, ST + 128, Nc);
    bn_f32<0><<<1024, blk, 0, stream>>>(A, ST + 0,   Nc, 1.f / Nc, gam_sc, bet_sc, nullptr);
    bn_f32<0><<<1024, blk, 0, stream>>>(B, ST + 128, Nc, 1.f / Nc, gam_g,  bet_g,  nullptr);
    // phi = leaky(bn(sconv(phi, W_gu, transposed pairs)))
    conv_mfma<64><<<Tc, dim3(512), 0, stream>>>(B, Wt_gu, ptr_gT, cnt_gT, el_gT,
                                                C, ST + 256, Nc);
    // s = leaky(bn(C)) + theta
    bn_f32<0><<<1024, blk, 0, stream>>>(C, ST + 256, Nc, 1.f / Nc, gam_gu, bet_gu, A);
    // s1 = leaky(bn(sconv(s, W_sum)))
    conv_sum_t<<<Tc, blk, 0, stream>>>(C, W_sum, ptr_g, cnt_g, el_g, D, ST + 384, Nc);
    bn1<<<256, blk, 0, stream>>>(D, ST + 384, Nc, 1.f / Nc, gam_sum, bet_sum);
    // out = sigmoid(bn(sconv(s1, W_up, inverse pairs)))
    conv_up_t<<<2048, blk, 0, stream>>>(D, W_up, ptr_up, cnt_up, el_up,
                                        outF, ST + 448, Nf);
    bn_f32<1><<<2048, blk, 0, stream>>>(outF, ST + 448, Nf, 1.f / Nf, gam_up, bet_up, nullptr);
}